// Round 22
// baseline (163.791 us; speedup 1.0000x reference)
//
#include <hip/hip_runtime.h>
#include <hip/hip_bf16.h>
#include <math.h>

// FAVOR+ (Performer) non-causal linear attention, b=4 h=8 n=8192 d=64 f=266.
// Round 22: revert to r20 (best passing). r21's rowmax removal failed because
// the reference's eps is a FLOOR relative to the row max (eps*e^m after
// un-normalization) — most features sit below it, so max subtraction is
// semantically required. Retained micro-deltas in p2 only: split out-GEMM
// accumulator (even/odd ks chains) + tree-structured rowmax (bit-exact).

typedef __attribute__((ext_vector_type(8))) short s16x8;
typedef __attribute__((ext_vector_type(4))) float f32x4;

#define MFMA16(a,b,c) __builtin_amdgcn_mfma_f32_16x16x32_bf16((a),(b),(c),0,0,0)

__device__ __forceinline__ unsigned short bf16rne(float x){
  union { __hip_bfloat16 b; unsigned short u; } cv;
  cv.b = __float2bfloat16(x);
  return cv.u;
}
__device__ __forceinline__ float bf16tof(unsigned short h){
  return __uint_as_float(((unsigned)h) << 16);
}
__device__ __forceinline__ float exp2_fast(float x){
#if __has_builtin(__builtin_amdgcn_exp2f)
  return __builtin_amdgcn_exp2f(x);
#else
  float r; asm("v_exp_f32 %0, %1" : "=v"(r) : "v"(x)); return r;
#endif
}
__device__ __forceinline__ float rcp_fast(float x){
#if __has_builtin(__builtin_amdgcn_rcpf)
  return __builtin_amdgcn_rcpf(x);
#else
  return 1.0f / x;
#endif
}
__device__ __forceinline__ void cvt_hl8(const float v[8], s16x8& h, s16x8& l){
  #pragma unroll
  for(int j=0;j<8;++j){
    unsigned short hh = bf16rne(v[j]);
    h[j] = (short)hh;
    l[j] = (short)bf16rne(v[j] - bf16tof(hh));
  }
}
__device__ __forceinline__ void cvt_h8(const float v[8], s16x8& h){
  #pragma unroll
  for(int j=0;j<8;++j) h[j] = (short)bf16rne(v[j]);
}

// ---------------- prep: scaled/padded proj hi (288 rows) ----------------
__global__ void fa21_prep(const float* __restrict__ proj, short* __restrict__ ph,
                          float pscale){
  int idx = blockIdx.x*256 + threadIdx.x;
  if(idx >= 288*64) return;
  int f = idx >> 6, dc = idx & 63;
  float v = (f < 266) ? proj[f*64 + dc]*pscale : 0.f;
  ph[idx] = (short)bf16rne(v);
}

// ---------------- phase 1: kp -> context partials + ksum partials ----------------
// (r16/r18/r20 version, verbatim — proven ~69us)
__global__ __launch_bounds__(1024,1) void fa21_p1(
    const float* __restrict__ kin, const float* __restrict__ vin,
    const short* __restrict__ pjh,
    float* __restrict__ ctx_part, float* __restrict__ ksum_part,
    float koff, float diagc){
  extern __shared__ char smem[];
  char* sph = smem;                     // 40960 (overlaid by ex[] in epilogue)
  char* skh = smem + 40960;             // 2 x 40960 kp double-buffer
  float* ex = (float*)smem;
  const int tid = threadIdx.x;
  const int w = tid >> 6, lane = tid & 63, g = lane >> 4, q = lane & 15;
  const int bid = blockIdx.x;
  const int head = bid & 31, chunk = bid >> 5;
  for(int i = tid; i < 2560; i += 1024){
    int f = i >> 3;
    int byt = (f*128 + (i & 7)*16) ^ ((f & 7) << 4);
    s16x8 vh8 = {0,0,0,0,0,0,0,0};
    if(f < 288) vh8 = ((const s16x8*)pjh)[i];
    *(s16x8*)(sph + byt) = vh8;
  }
  const int mtp = w & 3, fqp = w >> 2;
  const int et  = w & 3, fqc = w >> 2;
  f32x4 acc[5];
  #pragma unroll
  for(int a=0;a<5;++a){ f32x4 z = {0.f,0.f,0.f,0.f}; acc[a] = z; }
  float ksacc[5] = {0.f,0.f,0.f,0.f,0.f};
  const float* kbase = kin + (size_t)head*8192*64;
  const float* vbase = vin + (size_t)head*8192*64;
  const float* xp  = kbase + (size_t)(chunk*1024 + mtp*16 + q)*64 + g*8;
  const float* vp  = vbase + (size_t)(chunk*1024 + 8*g)*64 + et*16 + q;
  const float* vp2 = vp + 2048;
  float4 xa0 = *(const float4*)(xp);
  float4 xb0 = *(const float4*)(xp + 4);
  float4 xa1 = *(const float4*)(xp + 32);
  float4 xb1 = *(const float4*)(xp + 36);
  __syncthreads();
  #pragma unroll 1
  for(int it = 0; it < 16; ++it){
    char* kcur = skh + (it & 1)*40960;
    s16x8 xh[2], xl[2];
    float diag;
    {
      float v0[8] = {xa0.x,xa0.y,xa0.z,xa0.w,xb0.x,xb0.y,xb0.z,xb0.w};
      float v1[8] = {xa1.x,xa1.y,xa1.z,xa1.w,xb1.x,xb1.y,xb1.z,xb1.w};
      float ss = 0.f;
      #pragma unroll
      for(int j=0;j<8;++j){ ss += v0[j]*v0[j]; ss += v1[j]*v1[j]; }
      cvt_hl8(v0, xh[0], xl[0]);
      cvt_hl8(v1, xh[1], xl[1]);
      ss += __shfl_xor(ss, 16); ss += __shfl_xor(ss, 32);
      diag = ss * diagc;
    }
    float dro[4];
    #pragma unroll
    for(int i=0;i<4;++i) dro[i] = __shfl(diag, 4*g + i) - koff;
    s16x8 vh[2];
    {
      float vv[8];
      #pragma unroll
      for(int i2=0;i2<8;++i2) vv[i2] = vp[i2*64];
      cvt_h8(vv, vh[0]);
      #pragma unroll
      for(int i2=0;i2<8;++i2) vv[i2] = vp2[i2*64];
      cvt_h8(vv, vh[1]);
    }
    vp += 4096; vp2 += 4096;
    f32x4 S[5];
    #pragma unroll
    for(int t=0;t<5;++t){ f32x4 z = {0.f,0.f,0.f,0.f}; S[t] = z; }
    #pragma unroll
    for(int t=0; t<5; ++t){
      const int gt = fqp*5 + t;
      if(gt > 16) continue;
      const int f = gt*16 + q;
      #pragma unroll
      for(int ks=0; ks<2; ++ks){
        int byt = (f*128 + ks*64 + g*16) ^ ((f & 7) << 4);
        s16x8 bph = *(const s16x8*)(sph + byt);
        S[t] = MFMA16(xh[ks], bph, S[t]);
        S[t] = MFMA16(xl[ks], bph, S[t]);
      }
    }
    #pragma unroll
    for(int t=0; t<5; ++t){
      const int gt = fqp*5 + t;
      if(gt > 16) continue;
      const int f = gt*16 + q;
      float p[4];
      #pragma unroll
      for(int i=0;i<4;++i) p[i] = exp2_fast(S[t][i] - dro[i]);
      if(gt == 16){
        #pragma unroll
        for(int i=0;i<4;++i) p[i] = (q < 10) ? p[i] : 0.f;
      }
      ksacc[t] += p[0]+p[1]+p[2]+p[3];
      uint2 hv;
      hv.x = (unsigned)bf16rne(p[0]) | ((unsigned)bf16rne(p[1]) << 16);
      hv.y = (unsigned)bf16rne(p[2]) | ((unsigned)bf16rne(p[3]) << 16);
      int byt = (f*128 + (mtp*16 + 4*g)*2) ^ ((f & 7) << 4);
      *(uint2*)(kcur + byt) = hv;
    }
    xp += 4096;
    if(it < 15){
      xa0 = *(const float4*)(xp);
      xb0 = *(const float4*)(xp + 4);
      xa1 = *(const float4*)(xp + 32);
      xb1 = *(const float4*)(xp + 36);
    }
    __syncthreads();   // kp[cur] ready (single barrier per iter; dbuf)
    #pragma unroll
    for(int fm=0; fm<5; ++fm){
      const int gt = fqc*5 + fm;
      if(gt > 16) continue;
      const int fg = gt*16 + q;
      #pragma unroll
      for(int ks=0; ks<2; ++ks){
        int byt = (fg*128 + ks*64 + g*16) ^ ((fg & 7) << 4);
        s16x8 kf = *(const s16x8*)(kcur + byt);
        acc[fm] = MFMA16(kf, vh[ks], acc[fm]);
      }
    }
  }
  {
    float* cp = ctx_part + (size_t)bid*288*64;
    #pragma unroll
    for(int fm=0; fm<5; ++fm){
      const int gt = fqc*5 + fm;
      if(gt < 18){
        #pragma unroll
        for(int i=0;i<4;++i){
          int f = gt*16 + 4*g + i;
          cp[f*64 + et*16 + q] = acc[fm][i];
        }
      }
    }
  }
  __syncthreads();
  #pragma unroll
  for(int t=0; t<5; ++t){
    float s = ksacc[t];
    s += __shfl_xor(s, 16); s += __shfl_xor(s, 32);
    if(g == 0) ex[mtp*320 + (fqp*5 + t)*16 + q] = s;
  }
  __syncthreads();
  for(int i = tid; i < 288; i += 1024)
    ksum_part[(size_t)bid*288 + i] = ex[i] + ex[320+i] + ex[640+i] + ex[960+i];
}

// ---------------- reduce: sum 8 chunk partials -> ctx hi (e-major) + ksum ----------------
__global__ void fa21_reduce(const float* __restrict__ ctx_part, const float* __restrict__ ksum_part,
                            short* __restrict__ cth, float* __restrict__ ksum){
  int h = blockIdx.x >> 3, sl = blockIdx.x & 7, tid = threadIdx.x;
  for(int j = tid; j < 288*8; j += 256){
    int idx = sl*288*8 + j;
    float s = 0.f;
    #pragma unroll
    for(int c=0;c<8;++c) s += ctx_part[(size_t)(h + 32*c)*288*64 + idx];
    int f = idx >> 6, e = idx & 63;
    cth[(size_t)h*64*288 + e*288 + f] = (short)bf16rne(s);
  }
  if(sl == 0){
    for(int idx = tid; idx < 288; idx += 256){
      float s = 0.f;
      #pragma unroll
      for(int c=0;c<8;++c) s += ksum_part[(size_t)(h + 32*c)*288 + idx];
      ksum[h*288 + idx] = s;
    }
  }
}

// ---------------- phase 2: qp -> out (512-thr blocks, 2 blocks/CU) ----------------
// (r20 version + split oacc + tree rowmax)
__global__ __launch_bounds__(512,1) void fa21_p2(
    const float* __restrict__ qin,
    const short* __restrict__ pjh,
    const short* __restrict__ cth,
    const float* __restrict__ ksum, float* __restrict__ outp,
    float qoff, float qeps, float diagc){
  extern __shared__ char smem[];
  char* sct = smem;                        // 44032 ctxH [64 e][688B]
  char* sqp = smem + 44032;                // 18944 qp-hi [32 n][592B]
  float* rmx = (float*)(smem + 62976);     // [4 fq][32 n]
  float* dnb = (float*)(smem + 63488);     // [4 fq][32 n]
  float* sks = (float*)(smem + 64000);     // [320]
  const int tid = threadIdx.x;
  const int w = tid >> 6, lane = tid & 63, g = lane >> 4, q = lane & 15;
  const int bid = blockIdx.x;
  const int head = bid & 31, chunk = bid >> 5;
  const int mt2 = w & 1, fq = w >> 1;
  {
    const short* cb = cth + (size_t)head*18432;
    for(int i = tid; i < 2560; i += 512){
      int e = i / 40, j = i - e*40;
      int f0 = j*8;
      s16x8 v8 = {0,0,0,0,0,0,0,0};
      if(f0 < 288) v8 = *(const s16x8*)(cb + e*288 + f0);
      *(s16x8*)(sct + e*688 + f0*2) = v8;
    }
  }
  if(tid < 256){
    int r = tid >> 3, dwi = tid & 7;
    *(unsigned*)(sqp + r*592 + 544 + dwi*4) = 0u;
  }
  if(tid < 320) sks[tid] = (tid < 288) ? ksum[head*288 + tid] : 0.f;
  s16x8 aph[5][2];
  #pragma unroll
  for(int t=0; t<5; ++t){
    const int f = (fq*5 + t)*16 + q;
    #pragma unroll
    for(int ks=0; ks<2; ++ks){
      s16x8 v8 = {0,0,0,0,0,0,0,0};
      if(f < 288) v8 = *(const s16x8*)(pjh + f*64 + ks*32 + g*8);
      aph[t][ks] = v8;
    }
  }
  const float* qbase = qin + (size_t)head*8192*64;
  float* obase = outp + (size_t)head*8192*64;
  const float* xp = qbase + (size_t)(chunk*512 + mt2*16 + q)*64 + g*8;
  float* op = obase + (size_t)(chunk*512 + mt2*16 + 4*g)*64 + fq*16 + q;
  const int nrow = mt2*16 + q;
  float4 xa0 = *(const float4*)(xp);
  float4 xb0 = *(const float4*)(xp + 4);
  float4 xa1 = *(const float4*)(xp + 32);
  float4 xb1 = *(const float4*)(xp + 36);
  xp += 2048;
  __syncthreads();
  #pragma unroll 1
  for(int it=0; it<16; ++it){
    s16x8 xh[2], xl[2];
    float diag;
    {
      float v0[8] = {xa0.x,xa0.y,xa0.z,xa0.w,xb0.x,xb0.y,xb0.z,xb0.w};
      float v1[8] = {xa1.x,xa1.y,xa1.z,xa1.w,xb1.x,xb1.y,xb1.z,xb1.w};
      float ss = 0.f;
      #pragma unroll
      for(int j=0;j<8;++j){ ss += v0[j]*v0[j]; ss += v1[j]*v1[j]; }
      cvt_hl8(v0, xh[0], xl[0]);
      cvt_hl8(v1, xh[1], xl[1]);
      ss += __shfl_xor(ss, 16); ss += __shfl_xor(ss, 32);
      diag = ss * diagc;
    }
    if(it < 15){
      xa0 = *(const float4*)(xp);
      xb0 = *(const float4*)(xp + 4);
      xa1 = *(const float4*)(xp + 32);
      xb1 = *(const float4*)(xp + 36);
      xp += 2048;
    }
    f32x4 S[5];
    #pragma unroll
    for(int t=0;t<5;++t){ f32x4 z = {0.f,0.f,0.f,0.f}; S[t] = z; }
    #pragma unroll
    for(int t=0; t<5; ++t){
      if(fq*5 + t > 16) continue;
      #pragma unroll
      for(int ks=0; ks<2; ++ks){
        S[t] = MFMA16(aph[t][ks], xh[ks], S[t]);
        S[t] = MFMA16(aph[t][ks], xl[ks], S[t]);
      }
    }
    // rowmax: per-tile trees, then tree across tiles (bit-exact reassoc of fmax)
    float tm[5];
    #pragma unroll
    for(int t=0; t<5; ++t){
      const int gt = fq*5 + t;
      if(gt > 16){ tm[t] = -3e38f; continue; }
      if(gt == 16){
        const int fb = gt*16 + 4*g;
        float v0 = (fb + 0 < 266) ? S[t][0] : -3e38f;
        float v1 = (fb + 1 < 266) ? S[t][1] : -3e38f;
        float v2 = (fb + 2 < 266) ? S[t][2] : -3e38f;
        float v3 = (fb + 3 < 266) ? S[t][3] : -3e38f;
        tm[t] = fmaxf(fmaxf(v0, v1), fmaxf(v2, v3));
      } else {
        tm[t] = fmaxf(fmaxf(S[t][0], S[t][1]), fmaxf(S[t][2], S[t][3]));
      }
    }
    float m = fmaxf(fmaxf(fmaxf(tm[0], tm[1]), fmaxf(tm[2], tm[3])), tm[4]);
    m = fmaxf(m, __shfl_xor(m, 16));
    m = fmaxf(m, __shfl_xor(m, 32));
    if(lane < 16) rmx[fq*32 + nrow] = m;
    __syncthreads();  // bar1: rowmax partials ready
    float rm = fmaxf(fmaxf(rmx[nrow], rmx[32 + nrow]),
                     fmaxf(rmx[64 + nrow], rmx[96 + nrow]));
    const float dro = diag + rm - qoff;
    float dnp = 0.f;
    #pragma unroll
    for(int t=0; t<5; ++t){
      const int gt = fq*5 + t;
      if(gt > 16) continue;
      const int fb = gt*16 + 4*g;
      f32x4 kv = *(const f32x4*)(sks + fb);
      float pe[4];
      #pragma unroll
      for(int i=0;i<4;++i){
        pe[i] = exp2_fast(S[t][i] - dro) + qeps;
        dnp += pe[i] * kv[i];
      }
      uint2 hv;
      hv.x = (unsigned)bf16rne(pe[0]) | ((unsigned)bf16rne(pe[1]) << 16);
      hv.y = (unsigned)bf16rne(pe[2]) | ((unsigned)bf16rne(pe[3]) << 16);
      *(uint2*)(sqp + nrow*592 + fb*2) = hv;
    }
    dnp += __shfl_xor(dnp, 16);
    dnp += __shfl_xor(dnp, 32);
    if(lane < 16) dnb[fq*32 + nrow] = dnp;
    __syncthreads();  // bar2: qp + denom ready
    f32x4 dsum;
    {
      const int rb4 = mt2*16 + 4*g;
      f32x4 d0 = *(const f32x4*)(dnb +      rb4);
      f32x4 d1 = *(const f32x4*)(dnb + 32 + rb4);
      f32x4 d2 = *(const f32x4*)(dnb + 64 + rb4);
      f32x4 d3 = *(const f32x4*)(dnb + 96 + rb4);
      #pragma unroll
      for(int i=0;i<4;++i) dsum[i] = d0[i] + d1[i] + d2[i] + d3[i];
    }
    f32x4 oacc0 = {0.f,0.f,0.f,0.f};
    f32x4 oacc1 = {0.f,0.f,0.f,0.f};
    __builtin_amdgcn_s_setprio(1);
    #pragma unroll
    for(int ks=0; ks<9; ++ks){
      s16x8 ah = *(const s16x8*)(sqp + (mt2*16 + q)*592 + ks*64 + g*16);
      s16x8 ch = *(const s16x8*)(sct + (fq*16 + q)*688 + ks*64 + g*16);
      if(ks & 1) oacc1 = MFMA16(ah, ch, oacc1);
      else       oacc0 = MFMA16(ah, ch, oacc0);
    }
    __builtin_amdgcn_s_setprio(0);
    #pragma unroll
    for(int i=0;i<4;++i){
      op[i*64] = (oacc0[i] + oacc1[i]) * rcp_fast(dsum[i] + 1e-8f);
    }
    op += 2048;
  }
}

extern "C" void kernel_launch(void* const* d_in, const int* in_sizes, int n_in,
                              void* d_out, int out_size, void* d_ws, size_t ws_size,
                              hipStream_t stream){
  const float* q    = (const float*)d_in[0];
  const float* k    = (const float*)d_in[1];
  const float* v    = (const float*)d_in[2];
  const float* proj = (const float*)d_in[3];
  float* out = (float*)d_out;
  char* ws = (char*)d_ws;
  short* wproj_h = (short*)(ws);
  float* wctx    = (float*)(ws + 73728);
  float* wksump  = (float*)(ws + 18948096);          // 73728 + 256*288*64*4
  short* wct_h   = (short*)(ws + 19243008);          // + 256*288*4
  float* wksum   = (float*)(ws + 20422656);          // + 32*64*288*2

  const double LOG2E = 1.4426950408889634;
  const double ln_ratio = -0.5*log(266.0);
  float pscale = (float)(pow(64.0, -0.25) * LOG2E);
  float diagc  = (float)(0.0625 * LOG2E);
  float koff   = (float)((1e-4 + ln_ratio) * LOG2E);
  float qoff   = (float)(ln_ratio * LOG2E);
  float qeps   = (float)(1e-4 / sqrt(266.0));

  hipFuncSetAttribute((const void*)fa21_p1, hipFuncAttributeMaxDynamicSharedMemorySize, 122880);
  hipFuncSetAttribute((const void*)fa21_p2, hipFuncAttributeMaxDynamicSharedMemorySize, 65280);

  fa21_prep<<<72, 256, 0, stream>>>(proj, wproj_h, pscale);
  fa21_p1<<<256, 1024, 122880, stream>>>(k, v, wproj_h, wctx, wksump, koff, diagc);
  fa21_reduce<<<256, 256, 0, stream>>>(wctx, wksump, wct_h, wksum);
  fa21_p2<<<512, 512, 65280, stream>>>(q, wproj_h, wct_h, wksum, out,
                                       qoff, qeps, diagc);
}

// Round 23
// 158.200 us; speedup vs baseline: 1.0353x; 1.0353x over previous
//
#include <hip/hip_runtime.h>
#include <hip/hip_bf16.h>
#include <math.h>

// FAVOR+ (Performer) non-causal linear attention, b=4 h=8 n=8192 d=64 f=266.
// Round 23: r22 + drop X-lo product in p2's phi only (qp path). Calibrated
// from r11's measured delta (proj-lo drop on both paths: +0.0156 absmax);
// half the surface -> predicted absmax ~0.039 vs 0.05. phi 20->10 MFMA in p2,
// X cvt halved. p1 (kp path) keeps X-lo. Everything else = r22.

typedef __attribute__((ext_vector_type(8))) short s16x8;
typedef __attribute__((ext_vector_type(4))) float f32x4;

#define MFMA16(a,b,c) __builtin_amdgcn_mfma_f32_16x16x32_bf16((a),(b),(c),0,0,0)

__device__ __forceinline__ unsigned short bf16rne(float x){
  union { __hip_bfloat16 b; unsigned short u; } cv;
  cv.b = __float2bfloat16(x);
  return cv.u;
}
__device__ __forceinline__ float bf16tof(unsigned short h){
  return __uint_as_float(((unsigned)h) << 16);
}
__device__ __forceinline__ float exp2_fast(float x){
#if __has_builtin(__builtin_amdgcn_exp2f)
  return __builtin_amdgcn_exp2f(x);
#else
  float r; asm("v_exp_f32 %0, %1" : "=v"(r) : "v"(x)); return r;
#endif
}
__device__ __forceinline__ float rcp_fast(float x){
#if __has_builtin(__builtin_amdgcn_rcpf)
  return __builtin_amdgcn_rcpf(x);
#else
  return 1.0f / x;
#endif
}
__device__ __forceinline__ void cvt_hl8(const float v[8], s16x8& h, s16x8& l){
  #pragma unroll
  for(int j=0;j<8;++j){
    unsigned short hh = bf16rne(v[j]);
    h[j] = (short)hh;
    l[j] = (short)bf16rne(v[j] - bf16tof(hh));
  }
}
__device__ __forceinline__ void cvt_h8(const float v[8], s16x8& h){
  #pragma unroll
  for(int j=0;j<8;++j) h[j] = (short)bf16rne(v[j]);
}

// ---------------- prep: scaled/padded proj hi (288 rows) ----------------
__global__ void fa21_prep(const float* __restrict__ proj, short* __restrict__ ph,
                          float pscale){
  int idx = blockIdx.x*256 + threadIdx.x;
  if(idx >= 288*64) return;
  int f = idx >> 6, dc = idx & 63;
  float v = (f < 266) ? proj[f*64 + dc]*pscale : 0.f;
  ph[idx] = (short)bf16rne(v);
}

// ---------------- phase 1: kp -> context partials + ksum partials ----------------
// (r16/r18/r20/r22 version, verbatim — proven ~69us)
__global__ __launch_bounds__(1024,1) void fa21_p1(
    const float* __restrict__ kin, const float* __restrict__ vin,
    const short* __restrict__ pjh,
    float* __restrict__ ctx_part, float* __restrict__ ksum_part,
    float koff, float diagc){
  extern __shared__ char smem[];
  char* sph = smem;                     // 40960 (overlaid by ex[] in epilogue)
  char* skh = smem + 40960;             // 2 x 40960 kp double-buffer
  float* ex = (float*)smem;
  const int tid = threadIdx.x;
  const int w = tid >> 6, lane = tid & 63, g = lane >> 4, q = lane & 15;
  const int bid = blockIdx.x;
  const int head = bid & 31, chunk = bid >> 5;
  for(int i = tid; i < 2560; i += 1024){
    int f = i >> 3;
    int byt = (f*128 + (i & 7)*16) ^ ((f & 7) << 4);
    s16x8 vh8 = {0,0,0,0,0,0,0,0};
    if(f < 288) vh8 = ((const s16x8*)pjh)[i];
    *(s16x8*)(sph + byt) = vh8;
  }
  const int mtp = w & 3, fqp = w >> 2;
  const int et  = w & 3, fqc = w >> 2;
  f32x4 acc[5];
  #pragma unroll
  for(int a=0;a<5;++a){ f32x4 z = {0.f,0.f,0.f,0.f}; acc[a] = z; }
  float ksacc[5] = {0.f,0.f,0.f,0.f,0.f};
  const float* kbase = kin + (size_t)head*8192*64;
  const float* vbase = vin + (size_t)head*8192*64;
  const float* xp  = kbase + (size_t)(chunk*1024 + mtp*16 + q)*64 + g*8;
  const float* vp  = vbase + (size_t)(chunk*1024 + 8*g)*64 + et*16 + q;
  const float* vp2 = vp + 2048;
  float4 xa0 = *(const float4*)(xp);
  float4 xb0 = *(const float4*)(xp + 4);
  float4 xa1 = *(const float4*)(xp + 32);
  float4 xb1 = *(const float4*)(xp + 36);
  __syncthreads();
  #pragma unroll 1
  for(int it = 0; it < 16; ++it){
    char* kcur = skh + (it & 1)*40960;
    s16x8 xh[2], xl[2];
    float diag;
    {
      float v0[8] = {xa0.x,xa0.y,xa0.z,xa0.w,xb0.x,xb0.y,xb0.z,xb0.w};
      float v1[8] = {xa1.x,xa1.y,xa1.z,xa1.w,xb1.x,xb1.y,xb1.z,xb1.w};
      float ss = 0.f;
      #pragma unroll
      for(int j=0;j<8;++j){ ss += v0[j]*v0[j]; ss += v1[j]*v1[j]; }
      cvt_hl8(v0, xh[0], xl[0]);
      cvt_hl8(v1, xh[1], xl[1]);
      ss += __shfl_xor(ss, 16); ss += __shfl_xor(ss, 32);
      diag = ss * diagc;
    }
    float dro[4];
    #pragma unroll
    for(int i=0;i<4;++i) dro[i] = __shfl(diag, 4*g + i) - koff;
    s16x8 vh[2];
    {
      float vv[8];
      #pragma unroll
      for(int i2=0;i2<8;++i2) vv[i2] = vp[i2*64];
      cvt_h8(vv, vh[0]);
      #pragma unroll
      for(int i2=0;i2<8;++i2) vv[i2] = vp2[i2*64];
      cvt_h8(vv, vh[1]);
    }
    vp += 4096; vp2 += 4096;
    f32x4 S[5];
    #pragma unroll
    for(int t=0;t<5;++t){ f32x4 z = {0.f,0.f,0.f,0.f}; S[t] = z; }
    #pragma unroll
    for(int t=0; t<5; ++t){
      const int gt = fqp*5 + t;
      if(gt > 16) continue;
      const int f = gt*16 + q;
      #pragma unroll
      for(int ks=0; ks<2; ++ks){
        int byt = (f*128 + ks*64 + g*16) ^ ((f & 7) << 4);
        s16x8 bph = *(const s16x8*)(sph + byt);
        S[t] = MFMA16(xh[ks], bph, S[t]);
        S[t] = MFMA16(xl[ks], bph, S[t]);
      }
    }
    #pragma unroll
    for(int t=0; t<5; ++t){
      const int gt = fqp*5 + t;
      if(gt > 16) continue;
      const int f = gt*16 + q;
      float p[4];
      #pragma unroll
      for(int i=0;i<4;++i) p[i] = exp2_fast(S[t][i] - dro[i]);
      if(gt == 16){
        #pragma unroll
        for(int i=0;i<4;++i) p[i] = (q < 10) ? p[i] : 0.f;
      }
      ksacc[t] += p[0]+p[1]+p[2]+p[3];
      uint2 hv;
      hv.x = (unsigned)bf16rne(p[0]) | ((unsigned)bf16rne(p[1]) << 16);
      hv.y = (unsigned)bf16rne(p[2]) | ((unsigned)bf16rne(p[3]) << 16);
      int byt = (f*128 + (mtp*16 + 4*g)*2) ^ ((f & 7) << 4);
      *(uint2*)(kcur + byt) = hv;
    }
    xp += 4096;
    if(it < 15){
      xa0 = *(const float4*)(xp);
      xb0 = *(const float4*)(xp + 4);
      xa1 = *(const float4*)(xp + 32);
      xb1 = *(const float4*)(xp + 36);
    }
    __syncthreads();   // kp[cur] ready (single barrier per iter; dbuf)
    #pragma unroll
    for(int fm=0; fm<5; ++fm){
      const int gt = fqc*5 + fm;
      if(gt > 16) continue;
      const int fg = gt*16 + q;
      #pragma unroll
      for(int ks=0; ks<2; ++ks){
        int byt = (fg*128 + ks*64 + g*16) ^ ((fg & 7) << 4);
        s16x8 kf = *(const s16x8*)(kcur + byt);
        acc[fm] = MFMA16(kf, vh[ks], acc[fm]);
      }
    }
  }
  {
    float* cp = ctx_part + (size_t)bid*288*64;
    #pragma unroll
    for(int fm=0; fm<5; ++fm){
      const int gt = fqc*5 + fm;
      if(gt < 18){
        #pragma unroll
        for(int i=0;i<4;++i){
          int f = gt*16 + 4*g + i;
          cp[f*64 + et*16 + q] = acc[fm][i];
        }
      }
    }
  }
  __syncthreads();
  #pragma unroll
  for(int t=0; t<5; ++t){
    float s = ksacc[t];
    s += __shfl_xor(s, 16); s += __shfl_xor(s, 32);
    if(g == 0) ex[mtp*320 + (fqp*5 + t)*16 + q] = s;
  }
  __syncthreads();
  for(int i = tid; i < 288; i += 1024)
    ksum_part[(size_t)bid*288 + i] = ex[i] + ex[320+i] + ex[640+i] + ex[960+i];
}

// ---------------- reduce: sum 8 chunk partials -> ctx hi (e-major) + ksum ----------------
__global__ void fa21_reduce(const float* __restrict__ ctx_part, const float* __restrict__ ksum_part,
                            short* __restrict__ cth, float* __restrict__ ksum){
  int h = blockIdx.x >> 3, sl = blockIdx.x & 7, tid = threadIdx.x;
  for(int j = tid; j < 288*8; j += 256){
    int idx = sl*288*8 + j;
    float s = 0.f;
    #pragma unroll
    for(int c=0;c<8;++c) s += ctx_part[(size_t)(h + 32*c)*288*64 + idx];
    int f = idx >> 6, e = idx & 63;
    cth[(size_t)h*64*288 + e*288 + f] = (short)bf16rne(s);
  }
  if(sl == 0){
    for(int idx = tid; idx < 288; idx += 256){
      float s = 0.f;
      #pragma unroll
      for(int c=0;c<8;++c) s += ksum_part[(size_t)(h + 32*c)*288 + idx];
      ksum[h*288 + idx] = s;
    }
  }
}

// ---------------- phase 2: qp -> out (512-thr blocks, 2 blocks/CU) ----------------
// (r22 version; phi now 1-product: aph x X-hi only)
__global__ __launch_bounds__(512,1) void fa21_p2(
    const float* __restrict__ qin,
    const short* __restrict__ pjh,
    const short* __restrict__ cth,
    const float* __restrict__ ksum, float* __restrict__ outp,
    float qoff, float qeps, float diagc){
  extern __shared__ char smem[];
  char* sct = smem;                        // 44032 ctxH [64 e][688B]
  char* sqp = smem + 44032;                // 18944 qp-hi [32 n][592B]
  float* rmx = (float*)(smem + 62976);     // [4 fq][32 n]
  float* dnb = (float*)(smem + 63488);     // [4 fq][32 n]
  float* sks = (float*)(smem + 64000);     // [320]
  const int tid = threadIdx.x;
  const int w = tid >> 6, lane = tid & 63, g = lane >> 4, q = lane & 15;
  const int bid = blockIdx.x;
  const int head = bid & 31, chunk = bid >> 5;
  const int mt2 = w & 1, fq = w >> 1;
  {
    const short* cb = cth + (size_t)head*18432;
    for(int i = tid; i < 2560; i += 512){
      int e = i / 40, j = i - e*40;
      int f0 = j*8;
      s16x8 v8 = {0,0,0,0,0,0,0,0};
      if(f0 < 288) v8 = *(const s16x8*)(cb + e*288 + f0);
      *(s16x8*)(sct + e*688 + f0*2) = v8;
    }
  }
  if(tid < 256){
    int r = tid >> 3, dwi = tid & 7;
    *(unsigned*)(sqp + r*592 + 544 + dwi*4) = 0u;
  }
  if(tid < 320) sks[tid] = (tid < 288) ? ksum[head*288 + tid] : 0.f;
  s16x8 aph[5][2];
  #pragma unroll
  for(int t=0; t<5; ++t){
    const int f = (fq*5 + t)*16 + q;
    #pragma unroll
    for(int ks=0; ks<2; ++ks){
      s16x8 v8 = {0,0,0,0,0,0,0,0};
      if(f < 288) v8 = *(const s16x8*)(pjh + f*64 + ks*32 + g*8);
      aph[t][ks] = v8;
    }
  }
  const float* qbase = qin + (size_t)head*8192*64;
  float* obase = outp + (size_t)head*8192*64;
  const float* xp = qbase + (size_t)(chunk*512 + mt2*16 + q)*64 + g*8;
  float* op = obase + (size_t)(chunk*512 + mt2*16 + 4*g)*64 + fq*16 + q;
  const int nrow = mt2*16 + q;
  float4 xa0 = *(const float4*)(xp);
  float4 xb0 = *(const float4*)(xp + 4);
  float4 xa1 = *(const float4*)(xp + 32);
  float4 xb1 = *(const float4*)(xp + 36);
  xp += 2048;
  __syncthreads();
  #pragma unroll 1
  for(int it=0; it<16; ++it){
    s16x8 xh[2];
    float diag;
    {
      float v0[8] = {xa0.x,xa0.y,xa0.z,xa0.w,xb0.x,xb0.y,xb0.z,xb0.w};
      float v1[8] = {xa1.x,xa1.y,xa1.z,xa1.w,xb1.x,xb1.y,xb1.z,xb1.w};
      float ss = 0.f;
      #pragma unroll
      for(int j=0;j<8;++j){ ss += v0[j]*v0[j]; ss += v1[j]*v1[j]; }
      cvt_h8(v0, xh[0]);
      cvt_h8(v1, xh[1]);
      ss += __shfl_xor(ss, 16); ss += __shfl_xor(ss, 32);
      diag = ss * diagc;
    }
    if(it < 15){
      xa0 = *(const float4*)(xp);
      xb0 = *(const float4*)(xp + 4);
      xa1 = *(const float4*)(xp + 32);
      xb1 = *(const float4*)(xp + 36);
      xp += 2048;
    }
    f32x4 S[5];
    #pragma unroll
    for(int t=0;t<5;++t){ f32x4 z = {0.f,0.f,0.f,0.f}; S[t] = z; }
    #pragma unroll
    for(int t=0; t<5; ++t){
      if(fq*5 + t > 16) continue;
      #pragma unroll
      for(int ks=0; ks<2; ++ks){
        S[t] = MFMA16(aph[t][ks], xh[ks], S[t]);
      }
    }
    // rowmax: per-tile trees, then tree across tiles
    float tm[5];
    #pragma unroll
    for(int t=0; t<5; ++t){
      const int gt = fq*5 + t;
      if(gt > 16){ tm[t] = -3e38f; continue; }
      if(gt == 16){
        const int fb = gt*16 + 4*g;
        float v0 = (fb + 0 < 266) ? S[t][0] : -3e38f;
        float v1 = (fb + 1 < 266) ? S[t][1] : -3e38f;
        float v2 = (fb + 2 < 266) ? S[t][2] : -3e38f;
        float v3 = (fb + 3 < 266) ? S[t][3] : -3e38f;
        tm[t] = fmaxf(fmaxf(v0, v1), fmaxf(v2, v3));
      } else {
        tm[t] = fmaxf(fmaxf(S[t][0], S[t][1]), fmaxf(S[t][2], S[t][3]));
      }
    }
    float m = fmaxf(fmaxf(fmaxf(tm[0], tm[1]), fmaxf(tm[2], tm[3])), tm[4]);
    m = fmaxf(m, __shfl_xor(m, 16));
    m = fmaxf(m, __shfl_xor(m, 32));
    if(lane < 16) rmx[fq*32 + nrow] = m;
    __syncthreads();  // bar1: rowmax partials ready
    float rm = fmaxf(fmaxf(rmx[nrow], rmx[32 + nrow]),
                     fmaxf(rmx[64 + nrow], rmx[96 + nrow]));
    const float dro = diag + rm - qoff;
    float dnp = 0.f;
    #pragma unroll
    for(int t=0; t<5; ++t){
      const int gt = fq*5 + t;
      if(gt > 16) continue;
      const int fb = gt*16 + 4*g;
      f32x4 kv = *(const f32x4*)(sks + fb);
      float pe[4];
      #pragma unroll
      for(int i=0;i<4;++i){
        pe[i] = exp2_fast(S[t][i] - dro) + qeps;
        dnp += pe[i] * kv[i];
      }
      uint2 hv;
      hv.x = (unsigned)bf16rne(pe[0]) | ((unsigned)bf16rne(pe[1]) << 16);
      hv.y = (unsigned)bf16rne(pe[2]) | ((unsigned)bf16rne(pe[3]) << 16);
      *(uint2*)(sqp + nrow*592 + fb*2) = hv;
    }
    dnp += __shfl_xor(dnp, 16);
    dnp += __shfl_xor(dnp, 32);
    if(lane < 16) dnb[fq*32 + nrow] = dnp;
    __syncthreads();  // bar2: qp + denom ready
    f32x4 dsum;
    {
      const int rb4 = mt2*16 + 4*g;
      f32x4 d0 = *(const f32x4*)(dnb +      rb4);
      f32x4 d1 = *(const f32x4*)(dnb + 32 + rb4);
      f32x4 d2 = *(const f32x4*)(dnb + 64 + rb4);
      f32x4 d3 = *(const f32x4*)(dnb + 96 + rb4);
      #pragma unroll
      for(int i=0;i<4;++i) dsum[i] = d0[i] + d1[i] + d2[i] + d3[i];
    }
    f32x4 oacc0 = {0.f,0.f,0.f,0.f};
    f32x4 oacc1 = {0.f,0.f,0.f,0.f};
    __builtin_amdgcn_s_setprio(1);
    #pragma unroll
    for(int ks=0; ks<9; ++ks){
      s16x8 ah = *(const s16x8*)(sqp + (mt2*16 + q)*592 + ks*64 + g*16);
      s16x8 ch = *(const s16x8*)(sct + (fq*16 + q)*688 + ks*64 + g*16);
      if(ks & 1) oacc1 = MFMA16(ah, ch, oacc1);
      else       oacc0 = MFMA16(ah, ch, oacc0);
    }
    __builtin_amdgcn_s_setprio(0);
    #pragma unroll
    for(int i=0;i<4;++i){
      op[i*64] = (oacc0[i] + oacc1[i]) * rcp_fast(dsum[i] + 1e-8f);
    }
    op += 2048;
  }
}

extern "C" void kernel_launch(void* const* d_in, const int* in_sizes, int n_in,
                              void* d_out, int out_size, void* d_ws, size_t ws_size,
                              hipStream_t stream){
  const float* q    = (const float*)d_in[0];
  const float* k    = (const float*)d_in[1];
  const float* v    = (const float*)d_in[2];
  const float* proj = (const float*)d_in[3];
  float* out = (float*)d_out;
  char* ws = (char*)d_ws;
  short* wproj_h = (short*)(ws);
  float* wctx    = (float*)(ws + 73728);
  float* wksump  = (float*)(ws + 18948096);          // 73728 + 256*288*64*4
  short* wct_h   = (short*)(ws + 19243008);          // + 256*288*4
  float* wksum   = (float*)(ws + 20422656);          // + 32*64*288*2

  const double LOG2E = 1.4426950408889634;
  const double ln_ratio = -0.5*log(266.0);
  float pscale = (float)(pow(64.0, -0.25) * LOG2E);
  float diagc  = (float)(0.0625 * LOG2E);
  float koff   = (float)((1e-4 + ln_ratio) * LOG2E);
  float qoff   = (float)(ln_ratio * LOG2E);
  float qeps   = (float)(1e-4 / sqrt(266.0));

  hipFuncSetAttribute((const void*)fa21_p1, hipFuncAttributeMaxDynamicSharedMemorySize, 122880);
  hipFuncSetAttribute((const void*)fa21_p2, hipFuncAttributeMaxDynamicSharedMemorySize, 65280);

  fa21_prep<<<72, 256, 0, stream>>>(proj, wproj_h, pscale);
  fa21_p1<<<256, 1024, 122880, stream>>>(k, v, wproj_h, wctx, wksump, koff, diagc);
  fa21_reduce<<<256, 256, 0, stream>>>(wctx, wksump, wct_h, wksum);
  fa21_p2<<<512, 512, 65280, stream>>>(q, wproj_h, wct_h, wksum, out,
                                       qoff, qeps, diagc);
}

// Round 24
// 152.139 us; speedup vs baseline: 1.0766x; 1.0398x over previous
//
#include <hip/hip_runtime.h>
#include <hip/hip_bf16.h>
#include <math.h>

// FAVOR+ (Performer) non-causal linear attention, b=4 h=8 n=8192 d=64 f=266.
// Round 24: r23 + drop X-lo in p1's phi (k-path), symmetric to r23's q-path
// drop. Calibrated: each path drop = +0.0078 absmax (r11, r23 data points)
// -> predicted 0.0469 vs 0.05 threshold. p1 phi 20->10 MFMA, X cvt halved.
// diag remains exact (raw f32). If absmax > 0.05, revert to r23.

typedef __attribute__((ext_vector_type(8))) short s16x8;
typedef __attribute__((ext_vector_type(4))) float f32x4;

#define MFMA16(a,b,c) __builtin_amdgcn_mfma_f32_16x16x32_bf16((a),(b),(c),0,0,0)

__device__ __forceinline__ unsigned short bf16rne(float x){
  union { __hip_bfloat16 b; unsigned short u; } cv;
  cv.b = __float2bfloat16(x);
  return cv.u;
}
__device__ __forceinline__ float bf16tof(unsigned short h){
  return __uint_as_float(((unsigned)h) << 16);
}
__device__ __forceinline__ float exp2_fast(float x){
#if __has_builtin(__builtin_amdgcn_exp2f)
  return __builtin_amdgcn_exp2f(x);
#else
  float r; asm("v_exp_f32 %0, %1" : "=v"(r) : "v"(x)); return r;
#endif
}
__device__ __forceinline__ float rcp_fast(float x){
#if __has_builtin(__builtin_amdgcn_rcpf)
  return __builtin_amdgcn_rcpf(x);
#else
  return 1.0f / x;
#endif
}
__device__ __forceinline__ void cvt_h8(const float v[8], s16x8& h){
  #pragma unroll
  for(int j=0;j<8;++j) h[j] = (short)bf16rne(v[j]);
}

// ---------------- prep: scaled/padded proj hi (288 rows) ----------------
__global__ void fa21_prep(const float* __restrict__ proj, short* __restrict__ ph,
                          float pscale){
  int idx = blockIdx.x*256 + threadIdx.x;
  if(idx >= 288*64) return;
  int f = idx >> 6, dc = idx & 63;
  float v = (f < 266) ? proj[f*64 + dc]*pscale : 0.f;
  ph[idx] = (short)bf16rne(v);
}

// ---------------- phase 1: kp -> context partials + ksum partials ----------------
// grid 256 = 32 heads x 8 chunks, 1024 thr (16 waves), 16 iters x 64 rows.
// phi: 1-product (X-hi x projH). ctx: 1-product (kp-hi x V-hi). 1 barrier/iter.
__global__ __launch_bounds__(1024,1) void fa21_p1(
    const float* __restrict__ kin, const float* __restrict__ vin,
    const short* __restrict__ pjh,
    float* __restrict__ ctx_part, float* __restrict__ ksum_part,
    float koff, float diagc){
  extern __shared__ char smem[];
  char* sph = smem;                     // 40960 (overlaid by ex[] in epilogue)
  char* skh = smem + 40960;             // 2 x 40960 kp double-buffer
  float* ex = (float*)smem;
  const int tid = threadIdx.x;
  const int w = tid >> 6, lane = tid & 63, g = lane >> 4, q = lane & 15;
  const int bid = blockIdx.x;
  const int head = bid & 31, chunk = bid >> 5;
  for(int i = tid; i < 2560; i += 1024){
    int f = i >> 3;
    int byt = (f*128 + (i & 7)*16) ^ ((f & 7) << 4);
    s16x8 vh8 = {0,0,0,0,0,0,0,0};
    if(f < 288) vh8 = ((const s16x8*)pjh)[i];
    *(s16x8*)(sph + byt) = vh8;
  }
  const int mtp = w & 3, fqp = w >> 2;
  const int et  = w & 3, fqc = w >> 2;
  f32x4 acc[5];
  #pragma unroll
  for(int a=0;a<5;++a){ f32x4 z = {0.f,0.f,0.f,0.f}; acc[a] = z; }
  float ksacc[5] = {0.f,0.f,0.f,0.f,0.f};
  const float* kbase = kin + (size_t)head*8192*64;
  const float* vbase = vin + (size_t)head*8192*64;
  const float* xp  = kbase + (size_t)(chunk*1024 + mtp*16 + q)*64 + g*8;
  const float* vp  = vbase + (size_t)(chunk*1024 + 8*g)*64 + et*16 + q;
  const float* vp2 = vp + 2048;
  float4 xa0 = *(const float4*)(xp);
  float4 xb0 = *(const float4*)(xp + 4);
  float4 xa1 = *(const float4*)(xp + 32);
  float4 xb1 = *(const float4*)(xp + 36);
  __syncthreads();
  #pragma unroll 1
  for(int it = 0; it < 16; ++it){
    char* kcur = skh + (it & 1)*40960;
    s16x8 xh[2];
    float diag;
    {
      float v0[8] = {xa0.x,xa0.y,xa0.z,xa0.w,xb0.x,xb0.y,xb0.z,xb0.w};
      float v1[8] = {xa1.x,xa1.y,xa1.z,xa1.w,xb1.x,xb1.y,xb1.z,xb1.w};
      float ss = 0.f;
      #pragma unroll
      for(int j=0;j<8;++j){ ss += v0[j]*v0[j]; ss += v1[j]*v1[j]; }
      cvt_h8(v0, xh[0]);
      cvt_h8(v1, xh[1]);
      ss += __shfl_xor(ss, 16); ss += __shfl_xor(ss, 32);
      diag = ss * diagc;
    }
    float dro[4];
    #pragma unroll
    for(int i=0;i<4;++i) dro[i] = __shfl(diag, 4*g + i) - koff;
    s16x8 vh[2];
    {
      float vv[8];
      #pragma unroll
      for(int i2=0;i2<8;++i2) vv[i2] = vp[i2*64];
      cvt_h8(vv, vh[0]);
      #pragma unroll
      for(int i2=0;i2<8;++i2) vv[i2] = vp2[i2*64];
      cvt_h8(vv, vh[1]);
    }
    vp += 4096; vp2 += 4096;
    f32x4 S[5];
    #pragma unroll
    for(int t=0;t<5;++t){ f32x4 z = {0.f,0.f,0.f,0.f}; S[t] = z; }
    #pragma unroll
    for(int t=0; t<5; ++t){
      const int gt = fqp*5 + t;
      if(gt > 16) continue;
      const int f = gt*16 + q;
      #pragma unroll
      for(int ks=0; ks<2; ++ks){
        int byt = (f*128 + ks*64 + g*16) ^ ((f & 7) << 4);
        s16x8 bph = *(const s16x8*)(sph + byt);
        S[t] = MFMA16(xh[ks], bph, S[t]);
      }
    }
    #pragma unroll
    for(int t=0; t<5; ++t){
      const int gt = fqp*5 + t;
      if(gt > 16) continue;
      const int f = gt*16 + q;
      float p[4];
      #pragma unroll
      for(int i=0;i<4;++i) p[i] = exp2_fast(S[t][i] - dro[i]);
      if(gt == 16){
        #pragma unroll
        for(int i=0;i<4;++i) p[i] = (q < 10) ? p[i] : 0.f;
      }
      ksacc[t] += p[0]+p[1]+p[2]+p[3];
      uint2 hv;
      hv.x = (unsigned)bf16rne(p[0]) | ((unsigned)bf16rne(p[1]) << 16);
      hv.y = (unsigned)bf16rne(p[2]) | ((unsigned)bf16rne(p[3]) << 16);
      int byt = (f*128 + (mtp*16 + 4*g)*2) ^ ((f & 7) << 4);
      *(uint2*)(kcur + byt) = hv;
    }
    xp += 4096;
    if(it < 15){
      xa0 = *(const float4*)(xp);
      xb0 = *(const float4*)(xp + 4);
      xa1 = *(const float4*)(xp + 32);
      xb1 = *(const float4*)(xp + 36);
    }
    __syncthreads();   // kp[cur] ready (single barrier per iter; dbuf)
    #pragma unroll
    for(int fm=0; fm<5; ++fm){
      const int gt = fqc*5 + fm;
      if(gt > 16) continue;
      const int fg = gt*16 + q;
      #pragma unroll
      for(int ks=0; ks<2; ++ks){
        int byt = (fg*128 + ks*64 + g*16) ^ ((fg & 7) << 4);
        s16x8 kf = *(const s16x8*)(kcur + byt);
        acc[fm] = MFMA16(kf, vh[ks], acc[fm]);
      }
    }
  }
  {
    float* cp = ctx_part + (size_t)bid*288*64;
    #pragma unroll
    for(int fm=0; fm<5; ++fm){
      const int gt = fqc*5 + fm;
      if(gt < 18){
        #pragma unroll
        for(int i=0;i<4;++i){
          int f = gt*16 + 4*g + i;
          cp[f*64 + et*16 + q] = acc[fm][i];
        }
      }
    }
  }
  __syncthreads();
  #pragma unroll
  for(int t=0; t<5; ++t){
    float s = ksacc[t];
    s += __shfl_xor(s, 16); s += __shfl_xor(s, 32);
    if(g == 0) ex[mtp*320 + (fqp*5 + t)*16 + q] = s;
  }
  __syncthreads();
  for(int i = tid; i < 288; i += 1024)
    ksum_part[(size_t)bid*288 + i] = ex[i] + ex[320+i] + ex[640+i] + ex[960+i];
}

// ---------------- reduce: sum 8 chunk partials -> ctx hi (e-major) + ksum ----------------
__global__ void fa21_reduce(const float* __restrict__ ctx_part, const float* __restrict__ ksum_part,
                            short* __restrict__ cth, float* __restrict__ ksum){
  int h = blockIdx.x >> 3, sl = blockIdx.x & 7, tid = threadIdx.x;
  for(int j = tid; j < 288*8; j += 256){
    int idx = sl*288*8 + j;
    float s = 0.f;
    #pragma unroll
    for(int c=0;c<8;++c) s += ctx_part[(size_t)(h + 32*c)*288*64 + idx];
    int f = idx >> 6, e = idx & 63;
    cth[(size_t)h*64*288 + e*288 + f] = (short)bf16rne(s);
  }
  if(sl == 0){
    for(int idx = tid; idx < 288; idx += 256){
      float s = 0.f;
      #pragma unroll
      for(int c=0;c<8;++c) s += ksum_part[(size_t)(h + 32*c)*288 + idx];
      ksum[h*288 + idx] = s;
    }
  }
}

// ---------------- phase 2: qp -> out (512-thr blocks, 2 blocks/CU) ----------------
// (r23 version, verbatim — 1-product phi, tree rowmax, split oacc, setprio)
__global__ __launch_bounds__(512,1) void fa21_p2(
    const float* __restrict__ qin,
    const short* __restrict__ pjh,
    const short* __restrict__ cth,
    const float* __restrict__ ksum, float* __restrict__ outp,
    float qoff, float qeps, float diagc){
  extern __shared__ char smem[];
  char* sct = smem;                        // 44032 ctxH [64 e][688B]
  char* sqp = smem + 44032;                // 18944 qp-hi [32 n][592B]
  float* rmx = (float*)(smem + 62976);     // [4 fq][32 n]
  float* dnb = (float*)(smem + 63488);     // [4 fq][32 n]
  float* sks = (float*)(smem + 64000);     // [320]
  const int tid = threadIdx.x;
  const int w = tid >> 6, lane = tid & 63, g = lane >> 4, q = lane & 15;
  const int bid = blockIdx.x;
  const int head = bid & 31, chunk = bid >> 5;
  const int mt2 = w & 1, fq = w >> 1;
  {
    const short* cb = cth + (size_t)head*18432;
    for(int i = tid; i < 2560; i += 512){
      int e = i / 40, j = i - e*40;
      int f0 = j*8;
      s16x8 v8 = {0,0,0,0,0,0,0,0};
      if(f0 < 288) v8 = *(const s16x8*)(cb + e*288 + f0);
      *(s16x8*)(sct + e*688 + f0*2) = v8;
    }
  }
  if(tid < 256){
    int r = tid >> 3, dwi = tid & 7;
    *(unsigned*)(sqp + r*592 + 544 + dwi*4) = 0u;
  }
  if(tid < 320) sks[tid] = (tid < 288) ? ksum[head*288 + tid] : 0.f;
  s16x8 aph[5][2];
  #pragma unroll
  for(int t=0; t<5; ++t){
    const int f = (fq*5 + t)*16 + q;
    #pragma unroll
    for(int ks=0; ks<2; ++ks){
      s16x8 v8 = {0,0,0,0,0,0,0,0};
      if(f < 288) v8 = *(const s16x8*)(pjh + f*64 + ks*32 + g*8);
      aph[t][ks] = v8;
    }
  }
  const float* qbase = qin + (size_t)head*8192*64;
  float* obase = outp + (size_t)head*8192*64;
  const float* xp = qbase + (size_t)(chunk*512 + mt2*16 + q)*64 + g*8;
  float* op = obase + (size_t)(chunk*512 + mt2*16 + 4*g)*64 + fq*16 + q;
  const int nrow = mt2*16 + q;
  float4 xa0 = *(const float4*)(xp);
  float4 xb0 = *(const float4*)(xp + 4);
  float4 xa1 = *(const float4*)(xp + 32);
  float4 xb1 = *(const float4*)(xp + 36);
  xp += 2048;
  __syncthreads();
  #pragma unroll 1
  for(int it=0; it<16; ++it){
    s16x8 xh[2];
    float diag;
    {
      float v0[8] = {xa0.x,xa0.y,xa0.z,xa0.w,xb0.x,xb0.y,xb0.z,xb0.w};
      float v1[8] = {xa1.x,xa1.y,xa1.z,xa1.w,xb1.x,xb1.y,xb1.z,xb1.w};
      float ss = 0.f;
      #pragma unroll
      for(int j=0;j<8;++j){ ss += v0[j]*v0[j]; ss += v1[j]*v1[j]; }
      cvt_h8(v0, xh[0]);
      cvt_h8(v1, xh[1]);
      ss += __shfl_xor(ss, 16); ss += __shfl_xor(ss, 32);
      diag = ss * diagc;
    }
    if(it < 15){
      xa0 = *(const float4*)(xp);
      xb0 = *(const float4*)(xp + 4);
      xa1 = *(const float4*)(xp + 32);
      xb1 = *(const float4*)(xp + 36);
      xp += 2048;
    }
    f32x4 S[5];
    #pragma unroll
    for(int t=0;t<5;++t){ f32x4 z = {0.f,0.f,0.f,0.f}; S[t] = z; }
    #pragma unroll
    for(int t=0; t<5; ++t){
      if(fq*5 + t > 16) continue;
      #pragma unroll
      for(int ks=0; ks<2; ++ks){
        S[t] = MFMA16(aph[t][ks], xh[ks], S[t]);
      }
    }
    float tm[5];
    #pragma unroll
    for(int t=0; t<5; ++t){
      const int gt = fq*5 + t;
      if(gt > 16){ tm[t] = -3e38f; continue; }
      if(gt == 16){
        const int fb = gt*16 + 4*g;
        float v0 = (fb + 0 < 266) ? S[t][0] : -3e38f;
        float v1 = (fb + 1 < 266) ? S[t][1] : -3e38f;
        float v2 = (fb + 2 < 266) ? S[t][2] : -3e38f;
        float v3 = (fb + 3 < 266) ? S[t][3] : -3e38f;
        tm[t] = fmaxf(fmaxf(v0, v1), fmaxf(v2, v3));
      } else {
        tm[t] = fmaxf(fmaxf(S[t][0], S[t][1]), fmaxf(S[t][2], S[t][3]));
      }
    }
    float m = fmaxf(fmaxf(fmaxf(tm[0], tm[1]), fmaxf(tm[2], tm[3])), tm[4]);
    m = fmaxf(m, __shfl_xor(m, 16));
    m = fmaxf(m, __shfl_xor(m, 32));
    if(lane < 16) rmx[fq*32 + nrow] = m;
    __syncthreads();  // bar1: rowmax partials ready
    float rm = fmaxf(fmaxf(rmx[nrow], rmx[32 + nrow]),
                     fmaxf(rmx[64 + nrow], rmx[96 + nrow]));
    const float dro = diag + rm - qoff;
    float dnp = 0.f;
    #pragma unroll
    for(int t=0; t<5; ++t){
      const int gt = fq*5 + t;
      if(gt > 16) continue;
      const int fb = gt*16 + 4*g;
      f32x4 kv = *(const f32x4*)(sks + fb);
      float pe[4];
      #pragma unroll
      for(int i=0;i<4;++i){
        pe[i] = exp2_fast(S[t][i] - dro) + qeps;
        dnp += pe[i] * kv[i];
      }
      uint2 hv;
      hv.x = (unsigned)bf16rne(pe[0]) | ((unsigned)bf16rne(pe[1]) << 16);
      hv.y = (unsigned)bf16rne(pe[2]) | ((unsigned)bf16rne(pe[3]) << 16);
      *(uint2*)(sqp + nrow*592 + fb*2) = hv;
    }
    dnp += __shfl_xor(dnp, 16);
    dnp += __shfl_xor(dnp, 32);
    if(lane < 16) dnb[fq*32 + nrow] = dnp;
    __syncthreads();  // bar2: qp + denom ready
    f32x4 dsum;
    {
      const int rb4 = mt2*16 + 4*g;
      f32x4 d0 = *(const f32x4*)(dnb +      rb4);
      f32x4 d1 = *(const f32x4*)(dnb + 32 + rb4);
      f32x4 d2 = *(const f32x4*)(dnb + 64 + rb4);
      f32x4 d3 = *(const f32x4*)(dnb + 96 + rb4);
      #pragma unroll
      for(int i=0;i<4;++i) dsum[i] = d0[i] + d1[i] + d2[i] + d3[i];
    }
    f32x4 oacc0 = {0.f,0.f,0.f,0.f};
    f32x4 oacc1 = {0.f,0.f,0.f,0.f};
    __builtin_amdgcn_s_setprio(1);
    #pragma unroll
    for(int ks=0; ks<9; ++ks){
      s16x8 ah = *(const s16x8*)(sqp + (mt2*16 + q)*592 + ks*64 + g*16);
      s16x8 ch = *(const s16x8*)(sct + (fq*16 + q)*688 + ks*64 + g*16);
      if(ks & 1) oacc1 = MFMA16(ah, ch, oacc1);
      else       oacc0 = MFMA16(ah, ch, oacc0);
    }
    __builtin_amdgcn_s_setprio(0);
    #pragma unroll
    for(int i=0;i<4;++i){
      op[i*64] = (oacc0[i] + oacc1[i]) * rcp_fast(dsum[i] + 1e-8f);
    }
    op += 2048;
  }
}

extern "C" void kernel_launch(void* const* d_in, const int* in_sizes, int n_in,
                              void* d_out, int out_size, void* d_ws, size_t ws_size,
                              hipStream_t stream){
  const float* q    = (const float*)d_in[0];
  const float* k    = (const float*)d_in[1];
  const float* v    = (const float*)d_in[2];
  const float* proj = (const float*)d_in[3];
  float* out = (float*)d_out;
  char* ws = (char*)d_ws;
  short* wproj_h = (short*)(ws);
  float* wctx    = (float*)(ws + 73728);
  float* wksump  = (float*)(ws + 18948096);          // 73728 + 256*288*64*4
  short* wct_h   = (short*)(ws + 19243008);          // + 256*288*4
  float* wksum   = (float*)(ws + 20422656);          // + 32*64*288*2

  const double LOG2E = 1.4426950408889634;
  const double ln_ratio = -0.5*log(266.0);
  float pscale = (float)(pow(64.0, -0.25) * LOG2E);
  float diagc  = (float)(0.0625 * LOG2E);
  float koff   = (float)((1e-4 + ln_ratio) * LOG2E);
  float qoff   = (float)(ln_ratio * LOG2E);
  float qeps   = (float)(1e-4 / sqrt(266.0));

  hipFuncSetAttribute((const void*)fa21_p1, hipFuncAttributeMaxDynamicSharedMemorySize, 122880);
  hipFuncSetAttribute((const void*)fa21_p2, hipFuncAttributeMaxDynamicSharedMemorySize, 65280);

  fa21_prep<<<72, 256, 0, stream>>>(proj, wproj_h, pscale);
  fa21_p1<<<256, 1024, 122880, stream>>>(k, v, wproj_h, wctx, wksump, koff, diagc);
  fa21_reduce<<<256, 256, 0, stream>>>(wctx, wksump, wct_h, wksum);
  fa21_p2<<<512, 512, 65280, stream>>>(q, wproj_h, wct_h, wksum, out,
                                       qoff, qeps, diagc);
}